// Round 1
// baseline (4998.495 us; speedup 1.0000x reference)
//
#include <hip/hip_runtime.h>

// ---------------------------------------------------------------------------
// Decoder: B=8 T=512 D=1024 H=16 DH=64 L=4 C=10. Round 0: correct fp32
// baseline. GEMMs are 64x64-tile fp32 (no MFMA yet); attention is fused
// per-16-query-rows with LDS-staged K/V chunks (XOR-swizzled) and full-P
// softmax. Workspace: 5 buffers x 16MB = 80MB fp32.
// ---------------------------------------------------------------------------

#define BB   8
#define TT   512
#define DD   1024
#define HH   16
#define DHH  64
#define LLAY 4
#define MM   (BB*TT)          // 4096 rows
#define MD   ((size_t)MM*DD)  // 4,194,304 elements
#define INV_RD (1.0f/32.0f)   // 1/sqrt(D)
#define LNEPS 1e-5f

// x + pos (pos broadcast over batch). float4 over MD/4 elements.
__global__ __launch_bounds__(256) void add_pos_k(const float* __restrict__ x,
                                                 const float* __restrict__ pos,
                                                 float* __restrict__ out) {
  size_t i = (size_t)blockIdx.x * 256 + threadIdx.x;  // float4 index
  int dq  = (int)(i & 255);        // D/4 = 256 per row
  int row = (int)(i >> 8);
  int t   = row & (TT - 1);
  float4 a = ((const float4*)x)[i];
  float4 p = ((const float4*)pos)[(size_t)t * 256 + dq];
  a.x += p.x; a.y += p.y; a.z += p.z; a.w += p.w;
  ((float4*)out)[i] = a;
}

// LayerNorm: one block (256 thr) per row of D=1024. Biased variance (jnp.var).
__global__ __launch_bounds__(256) void ln_k(const float* __restrict__ in,
                                            float* __restrict__ out,
                                            const float* __restrict__ g,
                                            const float* __restrict__ bt) {
  int row = blockIdx.x;
  int t = threadIdx.x;
  const float4* r4 = (const float4*)(in + (size_t)row * DD);
  float4 v = r4[t];
  float s  = v.x + v.y + v.z + v.w;
  float ss = v.x*v.x + v.y*v.y + v.z*v.z + v.w*v.w;
#pragma unroll
  for (int off = 32; off > 0; off >>= 1) {
    s  += __shfl_down(s, off);
    ss += __shfl_down(ss, off);
  }
  __shared__ float red[8];
  int w = t >> 6;
  if ((t & 63) == 0) { red[w] = s; red[4 + w] = ss; }
  __syncthreads();
  s  = red[0] + red[1] + red[2] + red[3];
  ss = red[4] + red[5] + red[6] + red[7];
  float mean = s * (1.0f / DD);
  float var  = ss * (1.0f / DD) - mean * mean;
  float inv  = rsqrtf(var + LNEPS);
  float4 gv = ((const float4*)g)[t];
  float4 bv = ((const float4*)bt)[t];
  float4 o;
  o.x = (v.x - mean) * inv * gv.x + bv.x;
  o.y = (v.y - mean) * inv * gv.y + bv.y;
  o.z = (v.z - mean) * inv * gv.z + bv.z;
  o.w = (v.w - mean) * inv * gv.w + bv.w;
  ((float4*)(out + (size_t)row * DD))[t] = o;
}

// C[m,n] = sum_k A[m,k] * W[n,k]  (y = x @ W.T). M=4096, N=K=1024.
// 64x64 tile, BK=16, 256 threads, 4x4 micro-tile. LDS stored [k][m]/[k][n]
// so inner reads are contiguous b128 (A: broadcast, B: 2-way = free).
__global__ __launch_bounds__(256) void gemm_bt_k(const float* __restrict__ A,
                                                 const float* __restrict__ W,
                                                 float* __restrict__ C) {
  __shared__ float As[16][64];
  __shared__ float Bs[16][64];
  int t = threadIdx.x;
  int bn = blockIdx.x, bm = blockIdx.y;
  int lr = t >> 2;   // 0..63 tile row to stage
  int lc = t & 3;    // float4 group 0..3
  const float* arow = A + (size_t)(bm * 64 + lr) * DD;
  const float* wrow = W + (size_t)(bn * 64 + lr) * DD;
  int tx = t & 15, ty = t >> 4;
  float acc[4][4] = {{0.f}};
  for (int k0 = 0; k0 < DD; k0 += 16) {
    float4 av = *(const float4*)(arow + k0 + lc * 4);
    float4 wv = *(const float4*)(wrow + k0 + lc * 4);
    __syncthreads();   // previous iteration's reads done
    As[lc*4+0][lr] = av.x; As[lc*4+1][lr] = av.y; As[lc*4+2][lr] = av.z; As[lc*4+3][lr] = av.w;
    Bs[lc*4+0][lr] = wv.x; Bs[lc*4+1][lr] = wv.y; Bs[lc*4+2][lr] = wv.z; Bs[lc*4+3][lr] = wv.w;
    __syncthreads();
#pragma unroll
    for (int kk = 0; kk < 16; kk++) {
      float4 a4 = *(const float4*)&As[kk][ty * 4];
      float4 b4 = *(const float4*)&Bs[kk][tx * 4];
      acc[0][0] += a4.x*b4.x; acc[0][1] += a4.x*b4.y; acc[0][2] += a4.x*b4.z; acc[0][3] += a4.x*b4.w;
      acc[1][0] += a4.y*b4.x; acc[1][1] += a4.y*b4.y; acc[1][2] += a4.y*b4.z; acc[1][3] += a4.y*b4.w;
      acc[2][0] += a4.z*b4.x; acc[2][1] += a4.z*b4.y; acc[2][2] += a4.z*b4.z; acc[2][3] += a4.z*b4.w;
      acc[3][0] += a4.w*b4.x; acc[3][1] += a4.w*b4.y; acc[3][2] += a4.w*b4.z; acc[3][3] += a4.w*b4.w;
    }
  }
  float* crow = C + (size_t)(bm * 64 + ty * 4) * DD + bn * 64 + tx * 4;
#pragma unroll
  for (int ii = 0; ii < 4; ii++) {
    float4 o; o.x = acc[ii][0]; o.y = acc[ii][1]; o.z = acc[ii][2]; o.w = acc[ii][3];
    *(float4*)(crow + (size_t)ii * DD) = o;
  }
}

// Fused attention: block = 16 query rows of one (b,h). Scores (2x2 register
// tile) -> full P in LDS -> per-wave softmax -> P.V -> residual add.
// cross=1: K/V from inputs with (B,H,T,DH) layout + causal mask (key > q).
// cross=0: K/V from workspace with (B,T,H*DH) layout, no mask.
// KVs rows XOR-swizzled at float4 granularity to avoid stride-64 conflicts.
__global__ __launch_bounds__(256) void attn_k(const float* __restrict__ q,
                                              const float* __restrict__ kmat,
                                              const float* __restrict__ vmat,
                                              const float* __restrict__ resid,
                                              float* __restrict__ out,
                                              int cross) {
  __shared__ float Qs[16][64];
  __shared__ float KVs[64][64];
  __shared__ float Ps[16][514];   // +2 pad: phase-D broadcast reads conflict-free
  int t  = threadIdx.x;
  int qt = blockIdx.x;            // 0..31
  int bh = blockIdx.y;            // 0..127
  int b = bh >> 4, h = bh & 15;
  int q0 = qt * 16;
  size_t kvbase; int kvstride;
  if (cross) { kvbase = (size_t)bh * TT * DHH;          kvstride = DHH; }
  else       { kvbase = (size_t)b * TT * DD + h * DHH;  kvstride = DD;  }
  const float* kp = kmat + kvbase;
  const float* vp = vmat + kvbase;
  {
    int r = t >> 4, c4 = t & 15;
    float4 qv = *(const float4*)(q + (size_t)(b * TT + q0 + r) * DD + h * DHH + c4 * 4);
    *(float4*)&Qs[r][c4 * 4] = qv;
  }
  int i2 = t >> 5, j2 = t & 31;   // q-pair 0..7, key-pair 0..31
  for (int ch = 0; ch < 8; ch++) {
    __syncthreads();
    {
      int r = t >> 2;
      const float* krow = kp + (size_t)(ch * 64 + r) * kvstride;
#pragma unroll
      for (int c4 = (t & 3); c4 < 16; c4 += 4) {
        float4 kv = *(const float4*)(krow + c4 * 4);
        *(float4*)&KVs[r][((c4 ^ (r & 15)) << 2)] = kv;
      }
    }
    __syncthreads();
    float s00 = 0.f, s01 = 0.f, s10 = 0.f, s11 = 0.f;
    int r0 = 2 * j2, r1 = 2 * j2 + 1;
#pragma unroll
    for (int d4 = 0; d4 < 16; d4++) {
      float4 qa  = *(const float4*)&Qs[2 * i2][d4 << 2];
      float4 qb2 = *(const float4*)&Qs[2 * i2 + 1][d4 << 2];
      float4 ka  = *(const float4*)&KVs[r0][((d4 ^ (r0 & 15)) << 2)];
      float4 kb2 = *(const float4*)&KVs[r1][((d4 ^ (r1 & 15)) << 2)];
      s00 += qa.x*ka.x  + qa.y*ka.y  + qa.z*ka.z  + qa.w*ka.w;
      s01 += qa.x*kb2.x + qa.y*kb2.y + qa.z*kb2.z + qa.w*kb2.w;
      s10 += qb2.x*ka.x + qb2.y*ka.y + qb2.z*ka.z + qb2.w*ka.w;
      s11 += qb2.x*kb2.x+ qb2.y*kb2.y+ qb2.z*kb2.z+ qb2.w*kb2.w;
    }
    int kg  = ch * 64 + 2 * j2;
    int qg0 = q0 + 2 * i2, qg1 = qg0 + 1;
    const float NINF = -3.0e38f;
    Ps[2*i2  ][ch*64 + 2*j2    ] = (cross && (kg     > qg0)) ? NINF : s00 * INV_RD;
    Ps[2*i2  ][ch*64 + 2*j2 + 1] = (cross && (kg + 1 > qg0)) ? NINF : s01 * INV_RD;
    Ps[2*i2+1][ch*64 + 2*j2    ] = (cross && (kg     > qg1)) ? NINF : s10 * INV_RD;
    Ps[2*i2+1][ch*64 + 2*j2 + 1] = (cross && (kg + 1 > qg1)) ? NINF : s11 * INV_RD;
  }
  __syncthreads();
  {
    int w = t >> 6, lane = t & 63;
    for (int r = w; r < 16; r += 4) {
      float vals[8]; float mx = -3.4e38f;
#pragma unroll
      for (int c = 0; c < 8; c++) { vals[c] = Ps[r][c * 64 + lane]; mx = fmaxf(mx, vals[c]); }
#pragma unroll
      for (int off = 32; off > 0; off >>= 1) mx = fmaxf(mx, __shfl_xor(mx, off));
      float sum = 0.f;
#pragma unroll
      for (int c = 0; c < 8; c++) { vals[c] = __expf(vals[c] - mx); sum += vals[c]; }
#pragma unroll
      for (int off = 32; off > 0; off >>= 1) sum += __shfl_xor(sum, off);
      float inv = 1.0f / sum;
#pragma unroll
      for (int c = 0; c < 8; c++) Ps[r][c * 64 + lane] = vals[c] * inv;
    }
  }
  __syncthreads();
  int oi = t >> 4, oj = t & 15;   // q row, d4 group
  float ox = 0.f, oy = 0.f, oz = 0.f, ow = 0.f;
  for (int ch = 0; ch < 8; ch++) {
    __syncthreads();
    {
      int r = t >> 2;
      const float* vrow = vp + (size_t)(ch * 64 + r) * kvstride;
#pragma unroll
      for (int c4 = (t & 3); c4 < 16; c4 += 4) {
        float4 vv = *(const float4*)(vrow + c4 * 4);
        *(float4*)&KVs[r][((c4 ^ (r & 15)) << 2)] = vv;
      }
    }
    __syncthreads();
#pragma unroll
    for (int kk = 0; kk < 64; kk++) {
      float p = Ps[oi][ch * 64 + kk];
      float4 vv = *(const float4*)&KVs[kk][((oj ^ (kk & 15)) << 2)];
      ox += p * vv.x; oy += p * vv.y; oz += p * vv.z; ow += p * vv.w;
    }
  }
  size_t oidx = (size_t)(b * TT + q0 + oi) * DD + h * DHH + oj * 4;
  float4 rr = *(const float4*)(resid + oidx);
  float4 o4; o4.x = rr.x + ox; o4.y = rr.y + oy; o4.z = rr.z + oz; o4.w = rr.w + ow;
  *(float4*)(out + oidx) = o4;
}

// cur = relu(gemm_out + bias) + ln_out
__global__ __launch_bounds__(256) void fc_ep_k(const float* __restrict__ gout,
                                               const float* __restrict__ bias,
                                               const float* __restrict__ lnout,
                                               float* __restrict__ out) {
  size_t i = (size_t)blockIdx.x * 256 + threadIdx.x;  // float4 index
  int c4 = (int)(i & 255);
  float4 gv = ((const float4*)gout)[i];
  float4 bv = ((const float4*)bias)[c4];
  float4 lv = ((const float4*)lnout)[i];
  float4 o;
  o.x = fmaxf(gv.x + bv.x, 0.f) + lv.x;
  o.y = fmaxf(gv.y + bv.y, 0.f) + lv.y;
  o.z = fmaxf(gv.z + bv.z, 0.f) + lv.z;
  o.w = fmaxf(gv.w + bv.w, 0.f) + lv.w;
  ((float4*)out)[i] = o;
}

// Ordinal sigmoid head: b_j = cumsum(c0, c1^2..c8^2); probs via adjacent
// sigmoid differences. LDS transpose for coalesced C-interleaved writes.
__global__ __launch_bounds__(256) void head_k(const float* __restrict__ x,
                                              const float* __restrict__ cut,
                                              float* __restrict__ out) {
  __shared__ float obuf[2560];
  int t = threadIdx.x;
  size_t e = (size_t)blockIdx.x * 256 + t;
  float xv = x[e];
  float bj = cut[0];
  float sprev = 1.0f / (1.0f + __expf(xv - bj));  // sigmoid(bj - xv)
  obuf[t * 10 + 0] = sprev;
#pragma unroll
  for (int j = 1; j < 9; j++) {
    float cj = cut[j];
    bj += cj * cj;
    float sj = 1.0f / (1.0f + __expf(xv - bj));
    obuf[t * 10 + j] = sj - sprev;
    sprev = sj;
  }
  obuf[t * 10 + 9] = 1.0f - sprev;
  __syncthreads();
  size_t base = (size_t)blockIdx.x * 2560;
#pragma unroll
  for (int r = 0; r < 10; r++) out[base + r * 256 + t] = obuf[r * 256 + t];
}

extern "C" void kernel_launch(void* const* d_in, const int* in_sizes, int n_in,
                              void* d_out, int out_size, void* d_ws, size_t ws_size,
                              hipStream_t stream) {
  (void)in_sizes; (void)n_in; (void)out_size; (void)ws_size;
  const float* x    = (const float*)d_in[0];
  const float* kin  = (const float*)d_in[1];
  const float* vin  = (const float*)d_in[2];
  const float* pos  = (const float*)d_in[3];
  const float* Wq1  = (const float*)d_in[4];
  const float* Wk1  = (const float*)d_in[5];
  const float* Wv1  = (const float*)d_in[6];
  const float* Wq2  = (const float*)d_in[7];
  const float* Wfc  = (const float*)d_in[8];
  const float* bfc  = (const float*)d_in[9];
  const float* g1   = (const float*)d_in[10];
  const float* b1   = (const float*)d_in[11];
  const float* g2   = (const float*)d_in[12];
  const float* b2   = (const float*)d_in[13];
  const float* g3   = (const float*)d_in[14];
  const float* b3   = (const float*)d_in[15];
  const float* cut  = (const float*)d_in[16];
  float* out = (float*)d_out;

  // workspace: 5 x MD floats = 80 MB
  float* cur = (float*)d_ws;
  float* tmp = cur + MD;
  float* qb  = tmp + MD;
  float* kb  = qb + MD;
  float* vb  = kb + MD;

  dim3 b256(256);
  dim3 gg(DD / 64, MM / 64);   // (16, 64)
  dim3 ga(TT / 16, BB * HH);   // (32, 128)

  add_pos_k<<<MD / 1024, b256, 0, stream>>>(x, pos, cur);

  for (int i = 0; i < LLAY; i++) {
    const float* attn_in;
    if (i) {
      ln_k<<<MM, b256, 0, stream>>>(cur, tmp, g1 + (size_t)(i - 1) * DD, b1 + (size_t)(i - 1) * DD);
      attn_in = tmp;
    } else {
      attn_in = cur;
    }
    size_t wo = (size_t)i * DD * DD;
    gemm_bt_k<<<gg, b256, 0, stream>>>(attn_in, Wq1 + wo, qb);
    gemm_bt_k<<<gg, b256, 0, stream>>>(attn_in, Wk1 + wo, kb);
    gemm_bt_k<<<gg, b256, 0, stream>>>(attn_in, Wv1 + wo, vb);
    attn_k<<<ga, b256, 0, stream>>>(qb, kb, vb, attn_in, cur, 0);

    ln_k<<<MM, b256, 0, stream>>>(cur, tmp, g2 + (size_t)i * DD, b2 + (size_t)i * DD);
    gemm_bt_k<<<gg, b256, 0, stream>>>(tmp, Wq2 + wo, qb);
    attn_k<<<ga, b256, 0, stream>>>(qb, kin, vin, tmp, cur, 1);

    ln_k<<<MM, b256, 0, stream>>>(cur, tmp, g3 + (size_t)i * DD, b3 + (size_t)i * DD);
    gemm_bt_k<<<gg, b256, 0, stream>>>(tmp, Wfc + wo, qb);
    fc_ep_k<<<MD / 1024, b256, 0, stream>>>(qb, bfc + (size_t)i * DD, tmp, cur);
  }

  head_k<<<MD / 256, b256, 0, stream>>>(cur, cut, out);
}

// Round 2
// 3007.824 us; speedup vs baseline: 1.6618x; 1.6618x over previous
//
#include <hip/hip_runtime.h>

// ---------------------------------------------------------------------------
// Decoder: B=8 T=512 D=1024 H=16 DH=64 L=4 C=10.
// Round 1: GEMMs -> bf16 MFMA (16x16x32), m97-style 128x128 tile, BK=32,
// global_load_lds width 16, XOR chunk swizzle (2-way bank alias = free).
// Attention still fp32 (next round). Casts fused into ln/add_pos producers.
// Workspace: 80MB fp32 bufs + 8MB act_bf16 + 40MB weight_bf16 = 128MB.
// ---------------------------------------------------------------------------

#define BB   8
#define TT   512
#define DD   1024
#define HH   16
#define DHH  64
#define LLAY 4
#define MM   (BB*TT)          // 4096 rows
#define MD   ((size_t)MM*DD)  // 4,194,304 elements
#define INV_RD (1.0f/32.0f)   // 1/sqrt(D)
#define LNEPS 1e-5f

typedef unsigned short ushort_t;
typedef __attribute__((ext_vector_type(8))) short short8;
typedef __attribute__((ext_vector_type(4))) float floatx4;

__device__ inline ushort_t f2bf(float f) {
  unsigned u = __builtin_bit_cast(unsigned, f);
  unsigned r = (u + 0x7FFFu + ((u >> 16) & 1u)) >> 16;  // RNE
  return (ushort_t)r;
}

// x + pos (pos broadcast over batch); writes fp32 + bf16 copies.
__global__ __launch_bounds__(256) void add_pos_k(const float* __restrict__ x,
                                                 const float* __restrict__ pos,
                                                 float* __restrict__ out,
                                                 ushort_t* __restrict__ out_bf) {
  size_t i = (size_t)blockIdx.x * 256 + threadIdx.x;  // float4 index
  int dq  = (int)(i & 255);
  int row = (int)(i >> 8);
  int t   = row & (TT - 1);
  float4 a = ((const float4*)x)[i];
  float4 p = ((const float4*)pos)[(size_t)t * 256 + dq];
  a.x += p.x; a.y += p.y; a.z += p.z; a.w += p.w;
  ((float4*)out)[i] = a;
  ushort4 b; b.x = f2bf(a.x); b.y = f2bf(a.y); b.z = f2bf(a.z); b.w = f2bf(a.w);
  ((ushort4*)out_bf)[i] = b;
}

// fp32 -> bf16 cast (weights), 4 elems/thread.
__global__ __launch_bounds__(256) void cast_bf_k(const float* __restrict__ in,
                                                 ushort_t* __restrict__ out) {
  size_t i = (size_t)blockIdx.x * 256 + threadIdx.x;  // float4 index
  float4 v = ((const float4*)in)[i];
  ushort4 o; o.x = f2bf(v.x); o.y = f2bf(v.y); o.z = f2bf(v.z); o.w = f2bf(v.w);
  ((ushort4*)out)[i] = o;
}

// LayerNorm: one block per row of D=1024; writes fp32 + bf16 copies.
__global__ __launch_bounds__(256) void ln_k(const float* __restrict__ in,
                                            float* __restrict__ out,
                                            ushort_t* __restrict__ out_bf,
                                            const float* __restrict__ g,
                                            const float* __restrict__ bt) {
  int row = blockIdx.x;
  int t = threadIdx.x;
  const float4* r4 = (const float4*)(in + (size_t)row * DD);
  float4 v = r4[t];
  float s  = v.x + v.y + v.z + v.w;
  float ss = v.x*v.x + v.y*v.y + v.z*v.z + v.w*v.w;
#pragma unroll
  for (int off = 32; off > 0; off >>= 1) {
    s  += __shfl_down(s, off);
    ss += __shfl_down(ss, off);
  }
  __shared__ float red[8];
  int w = t >> 6;
  if ((t & 63) == 0) { red[w] = s; red[4 + w] = ss; }
  __syncthreads();
  s  = red[0] + red[1] + red[2] + red[3];
  ss = red[4] + red[5] + red[6] + red[7];
  float mean = s * (1.0f / DD);
  float var  = ss * (1.0f / DD) - mean * mean;
  float inv  = rsqrtf(var + LNEPS);
  float4 gv = ((const float4*)g)[t];
  float4 bv = ((const float4*)bt)[t];
  float4 o;
  o.x = (v.x - mean) * inv * gv.x + bv.x;
  o.y = (v.y - mean) * inv * gv.y + bv.y;
  o.z = (v.z - mean) * inv * gv.z + bv.z;
  o.w = (v.w - mean) * inv * gv.w + bv.w;
  ((float4*)(out + (size_t)row * DD))[t] = o;
  ushort4 ob; ob.x = f2bf(o.x); ob.y = f2bf(o.y); ob.z = f2bf(o.z); ob.w = f2bf(o.w);
  ((ushort4*)(out_bf + (size_t)row * DD))[t] = ob;
}

// C[m,n] = sum_k A[m,k]*W[n,k], A/W bf16, C fp32. M=4096 N=K=1024.
// 128x128 tile, BK=32, 4 waves each 64x64 (4x4 of 16x16x32 MFMA).
// LDS [row][4 chunks of 8 bf16]; chunk slot XOR-swizzled by (row>>1)&3 so
// fragment ds_read_b128 is 2-way bank aliased (free). Staging via
// global_load_lds width 16 (wave-uniform base + lane*16 -> e*16 layout).
__global__ __launch_bounds__(256) void gemm_mfma_bt_k(const ushort_t* __restrict__ A,
                                                      const ushort_t* __restrict__ W,
                                                      float* __restrict__ C) {
  __shared__ ushort_t As[128 * 32];
  __shared__ ushort_t Bs[128 * 32];
  int t = threadIdx.x;
  int n0 = blockIdx.x * 128, m0 = blockIdx.y * 128;
  int lane = t & 63, w = t >> 6;
  int wm = (w >> 1) * 64, wn = (w & 1) * 64;
  int fr = lane & 15, q = lane >> 4;
  const short8* ap[4]; const short8* bp[4];
#pragma unroll
  for (int i = 0; i < 4; i++) {
    int r  = wm + i * 16 + fr;
    int rn = wn + i * 16 + fr;
    ap[i] = (const short8*)(As + r  * 32 + ((q ^ ((r  >> 1) & 3)) * 8));
    bp[i] = (const short8*)(Bs + rn * 32 + ((q ^ ((rn >> 1) & 3)) * 8));
  }
  auto* As3 = (__attribute__((address_space(3))) ushort_t*)As;
  auto* Bs3 = (__attribute__((address_space(3))) ushort_t*)Bs;
  floatx4 acc[4][4] = {};
  for (int k0 = 0; k0 < DD; k0 += 32) {
    __syncthreads();
#pragma unroll
    for (int j = 0; j < 2; j++) {
      int e = t + j * 256;          // 16B chunk index 0..511
      int row = e >> 2, slot = e & 3;
      int c = slot ^ ((row >> 1) & 3);
      const ushort_t* asrc = A + (size_t)(m0 + row) * DD + k0 + c * 8;
      const ushort_t* wsrc = W + (size_t)(n0 + row) * DD + k0 + c * 8;
      __builtin_amdgcn_global_load_lds(
          (const __attribute__((address_space(1))) unsigned*)asrc,
          (__attribute__((address_space(3))) unsigned*)(As3 + e * 8), 16, 0, 0);
      __builtin_amdgcn_global_load_lds(
          (const __attribute__((address_space(1))) unsigned*)wsrc,
          (__attribute__((address_space(3))) unsigned*)(Bs3 + e * 8), 16, 0, 0);
    }
    __syncthreads();
    short8 af[4], bf[4];
#pragma unroll
    for (int i = 0; i < 4; i++) { af[i] = *ap[i]; bf[i] = *bp[i]; }
#pragma unroll
    for (int i = 0; i < 4; i++)
#pragma unroll
      for (int j = 0; j < 4; j++)
        acc[i][j] = __builtin_amdgcn_mfma_f32_16x16x32_bf16(af[i], bf[j], acc[i][j], 0, 0, 0);
  }
  int orow = m0 + wm + q * 4;       // C/D: row=(lane>>4)*4+reg, col=lane&15
  int ocol = n0 + wn + fr;
#pragma unroll
  for (int i = 0; i < 4; i++)
#pragma unroll
    for (int j = 0; j < 4; j++)
#pragma unroll
      for (int rr = 0; rr < 4; rr++)
        C[(size_t)(orow + i * 16 + rr) * DD + ocol + j * 16] = acc[i][j][rr];
}

// Fused attention (fp32, unchanged this round).
__global__ __launch_bounds__(256) void attn_k(const float* __restrict__ q,
                                              const float* __restrict__ kmat,
                                              const float* __restrict__ vmat,
                                              const float* __restrict__ resid,
                                              float* __restrict__ out,
                                              int cross) {
  __shared__ float Qs[16][64];
  __shared__ float KVs[64][64];
  __shared__ float Ps[16][514];
  int t  = threadIdx.x;
  int qt = blockIdx.x;
  int bh = blockIdx.y;
  int b = bh >> 4, h = bh & 15;
  int q0 = qt * 16;
  size_t kvbase; int kvstride;
  if (cross) { kvbase = (size_t)bh * TT * DHH;          kvstride = DHH; }
  else       { kvbase = (size_t)b * TT * DD + h * DHH;  kvstride = DD;  }
  const float* kp = kmat + kvbase;
  const float* vp = vmat + kvbase;
  {
    int r = t >> 4, c4 = t & 15;
    float4 qv = *(const float4*)(q + (size_t)(b * TT + q0 + r) * DD + h * DHH + c4 * 4);
    *(float4*)&Qs[r][c4 * 4] = qv;
  }
  int i2 = t >> 5, j2 = t & 31;
  for (int ch = 0; ch < 8; ch++) {
    __syncthreads();
    {
      int r = t >> 2;
      const float* krow = kp + (size_t)(ch * 64 + r) * kvstride;
#pragma unroll
      for (int c4 = (t & 3); c4 < 16; c4 += 4) {
        float4 kv = *(const float4*)(krow + c4 * 4);
        *(float4*)&KVs[r][((c4 ^ (r & 15)) << 2)] = kv;
      }
    }
    __syncthreads();
    float s00 = 0.f, s01 = 0.f, s10 = 0.f, s11 = 0.f;
    int r0 = 2 * j2, r1 = 2 * j2 + 1;
#pragma unroll
    for (int d4 = 0; d4 < 16; d4++) {
      float4 qa  = *(const float4*)&Qs[2 * i2][d4 << 2];
      float4 qb2 = *(const float4*)&Qs[2 * i2 + 1][d4 << 2];
      float4 ka  = *(const float4*)&KVs[r0][((d4 ^ (r0 & 15)) << 2)];
      float4 kb2 = *(const float4*)&KVs[r1][((d4 ^ (r1 & 15)) << 2)];
      s00 += qa.x*ka.x  + qa.y*ka.y  + qa.z*ka.z  + qa.w*ka.w;
      s01 += qa.x*kb2.x + qa.y*kb2.y + qa.z*kb2.z + qa.w*kb2.w;
      s10 += qb2.x*ka.x + qb2.y*ka.y + qb2.z*ka.z + qb2.w*ka.w;
      s11 += qb2.x*kb2.x+ qb2.y*kb2.y+ qb2.z*kb2.z+ qb2.w*kb2.w;
    }
    int kg  = ch * 64 + 2 * j2;
    int qg0 = q0 + 2 * i2, qg1 = qg0 + 1;
    const float NINF = -3.0e38f;
    Ps[2*i2  ][ch*64 + 2*j2    ] = (cross && (kg     > qg0)) ? NINF : s00 * INV_RD;
    Ps[2*i2  ][ch*64 + 2*j2 + 1] = (cross && (kg + 1 > qg0)) ? NINF : s01 * INV_RD;
    Ps[2*i2+1][ch*64 + 2*j2    ] = (cross && (kg     > qg1)) ? NINF : s10 * INV_RD;
    Ps[2*i2+1][ch*64 + 2*j2 + 1] = (cross && (kg + 1 > qg1)) ? NINF : s11 * INV_RD;
  }
  __syncthreads();
  {
    int w = t >> 6, lane = t & 63;
    for (int r = w; r < 16; r += 4) {
      float vals[8]; float mx = -3.4e38f;
#pragma unroll
      for (int c = 0; c < 8; c++) { vals[c] = Ps[r][c * 64 + lane]; mx = fmaxf(mx, vals[c]); }
#pragma unroll
      for (int off = 32; off > 0; off >>= 1) mx = fmaxf(mx, __shfl_xor(mx, off));
      float sum = 0.f;
#pragma unroll
      for (int c = 0; c < 8; c++) { vals[c] = __expf(vals[c] - mx); sum += vals[c]; }
#pragma unroll
      for (int off = 32; off > 0; off >>= 1) sum += __shfl_xor(sum, off);
      float inv = 1.0f / sum;
#pragma unroll
      for (int c = 0; c < 8; c++) Ps[r][c * 64 + lane] = vals[c] * inv;
    }
  }
  __syncthreads();
  int oi = t >> 4, oj = t & 15;
  float ox = 0.f, oy = 0.f, oz = 0.f, ow = 0.f;
  for (int ch = 0; ch < 8; ch++) {
    __syncthreads();
    {
      int r = t >> 2;
      const float* vrow = vp + (size_t)(ch * 64 + r) * kvstride;
#pragma unroll
      for (int c4 = (t & 3); c4 < 16; c4 += 4) {
        float4 vv = *(const float4*)(vrow + c4 * 4);
        *(float4*)&KVs[r][((c4 ^ (r & 15)) << 2)] = vv;
      }
    }
    __syncthreads();
#pragma unroll
    for (int kk = 0; kk < 64; kk++) {
      float p = Ps[oi][ch * 64 + kk];
      float4 vv = *(const float4*)&KVs[kk][((oj ^ (kk & 15)) << 2)];
      ox += p * vv.x; oy += p * vv.y; oz += p * vv.z; ow += p * vv.w;
    }
  }
  size_t oidx = (size_t)(b * TT + q0 + oi) * DD + h * DHH + oj * 4;
  float4 rr = *(const float4*)(resid + oidx);
  float4 o4; o4.x = rr.x + ox; o4.y = rr.y + oy; o4.z = rr.z + oz; o4.w = rr.w + ow;
  *(float4*)(out + oidx) = o4;
}

// cur = relu(gemm_out + bias) + ln_out
__global__ __launch_bounds__(256) void fc_ep_k(const float* __restrict__ gout,
                                               const float* __restrict__ bias,
                                               const float* __restrict__ lnout,
                                               float* __restrict__ out) {
  size_t i = (size_t)blockIdx.x * 256 + threadIdx.x;
  int c4 = (int)(i & 255);
  float4 gv = ((const float4*)gout)[i];
  float4 bv = ((const float4*)bias)[c4];
  float4 lv = ((const float4*)lnout)[i];
  float4 o;
  o.x = fmaxf(gv.x + bv.x, 0.f) + lv.x;
  o.y = fmaxf(gv.y + bv.y, 0.f) + lv.y;
  o.z = fmaxf(gv.z + bv.z, 0.f) + lv.z;
  o.w = fmaxf(gv.w + bv.w, 0.f) + lv.w;
  ((float4*)out)[i] = o;
}

// Ordinal sigmoid head.
__global__ __launch_bounds__(256) void head_k(const float* __restrict__ x,
                                              const float* __restrict__ cut,
                                              float* __restrict__ out) {
  __shared__ float obuf[2560];
  int t = threadIdx.x;
  size_t e = (size_t)blockIdx.x * 256 + t;
  float xv = x[e];
  float bj = cut[0];
  float sprev = 1.0f / (1.0f + __expf(xv - bj));
  obuf[t * 10 + 0] = sprev;
#pragma unroll
  for (int j = 1; j < 9; j++) {
    float cj = cut[j];
    bj += cj * cj;
    float sj = 1.0f / (1.0f + __expf(xv - bj));
    obuf[t * 10 + j] = sj - sprev;
    sprev = sj;
  }
  obuf[t * 10 + 9] = 1.0f - sprev;
  __syncthreads();
  size_t base = (size_t)blockIdx.x * 2560;
#pragma unroll
  for (int r = 0; r < 10; r++) out[base + r * 256 + t] = obuf[r * 256 + t];
}

extern "C" void kernel_launch(void* const* d_in, const int* in_sizes, int n_in,
                              void* d_out, int out_size, void* d_ws, size_t ws_size,
                              hipStream_t stream) {
  (void)in_sizes; (void)n_in; (void)out_size; (void)ws_size;
  const float* x    = (const float*)d_in[0];
  const float* kin  = (const float*)d_in[1];
  const float* vin  = (const float*)d_in[2];
  const float* pos  = (const float*)d_in[3];
  const float* Wq1  = (const float*)d_in[4];
  const float* Wk1  = (const float*)d_in[5];
  const float* Wv1  = (const float*)d_in[6];
  const float* Wq2  = (const float*)d_in[7];
  const float* Wfc  = (const float*)d_in[8];
  const float* bfc  = (const float*)d_in[9];
  const float* g1   = (const float*)d_in[10];
  const float* b1   = (const float*)d_in[11];
  const float* g2   = (const float*)d_in[12];
  const float* b2   = (const float*)d_in[13];
  const float* g3   = (const float*)d_in[14];
  const float* b3   = (const float*)d_in[15];
  const float* cut  = (const float*)d_in[16];
  float* out = (float*)d_out;

  // ws: 5 fp32 bufs (80MB) + act_bf (8MB) + 5 weight_bf (40MB) = 128MB
  float* cur = (float*)d_ws;
  float* tmp = cur + MD;
  float* qb  = tmp + MD;
  float* kb  = qb + MD;
  float* vb  = kb + MD;
  ushort_t* act_bf = (ushort_t*)(vb + MD);
  ushort_t* wbf[5];
  wbf[0] = act_bf + MD;
  for (int i = 1; i < 5; i++) wbf[i] = wbf[i - 1] + (size_t)LLAY * DD * DD;
  const float* wsrc[5] = {Wq1, Wk1, Wv1, Wq2, Wfc};

  dim3 b256(256);
  dim3 gg(DD / 128, MM / 128);   // (8, 32)
  dim3 ga(TT / 16, BB * HH);     // (32, 128)

  // weight casts: L*D*D/4 float4s per tensor
  for (int i = 0; i < 5; i++)
    cast_bf_k<<<(LLAY * DD * DD) / 1024, b256, 0, stream>>>(wsrc[i], wbf[i]);

  add_pos_k<<<MD / 1024, b256, 0, stream>>>(x, pos, cur, act_bf);

  for (int i = 0; i < LLAY; i++) {
    const float* attn_in;
    if (i) {
      ln_k<<<MM, b256, 0, stream>>>(cur, tmp, act_bf, g1 + (size_t)(i - 1) * DD, b1 + (size_t)(i - 1) * DD);
      attn_in = tmp;
    } else {
      attn_in = cur;   // act_bf already holds bf16(cur) from add_pos_k
    }
    size_t wo = (size_t)i * DD * DD;
    gemm_mfma_bt_k<<<gg, b256, 0, stream>>>(act_bf, wbf[0] + wo, qb);
    gemm_mfma_bt_k<<<gg, b256, 0, stream>>>(act_bf, wbf[1] + wo, kb);
    gemm_mfma_bt_k<<<gg, b256, 0, stream>>>(act_bf, wbf[2] + wo, vb);
    attn_k<<<ga, b256, 0, stream>>>(qb, kb, vb, attn_in, cur, 0);

    ln_k<<<MM, b256, 0, stream>>>(cur, tmp, act_bf, g2 + (size_t)i * DD, b2 + (size_t)i * DD);
    gemm_mfma_bt_k<<<gg, b256, 0, stream>>>(act_bf, wbf[3] + wo, qb);
    attn_k<<<ga, b256, 0, stream>>>(qb, kin, vin, tmp, cur, 1);

    ln_k<<<MM, b256, 0, stream>>>(cur, tmp, act_bf, g3 + (size_t)i * DD, b3 + (size_t)i * DD);
    gemm_mfma_bt_k<<<gg, b256, 0, stream>>>(act_bf, wbf[4] + wo, qb);
    fc_ep_k<<<MD / 1024, b256, 0, stream>>>(qb, bfc + (size_t)i * DD, tmp, cur);
  }

  head_k<<<MD / 256, b256, 0, stream>>>(cur, cut, out);
}

// Round 3
// 1268.012 us; speedup vs baseline: 3.9420x; 2.3721x over previous
//
#include <hip/hip_runtime.h>

// ---------------------------------------------------------------------------
// Decoder: B=8 T=512 D=1024 H=16 DH=64 L=4 C=10.
// Round 2: attention -> bf16 MFMA flash-style. Block = 64 q-rows of one
// (b,h); K chunk natural + V chunk transposed in LDS (XOR chunk swizzle);
// QK^T MFMA -> online softmax (register state) -> P LDS round-trip ->
// PV MFMA. Cross-attn: triangular chunk skip + diagonal-only mask.
// GEMMs emit bf16 directly for attention consumers.
// Workspace layout (120 MB): cur 16 + tmp 16 + act_bf 8 + qbf 8 +
// kv/fc-alias 16 + kinbf 8 + vinbf 8 + wbf 40.
// ---------------------------------------------------------------------------

#define BB   8
#define TT   512
#define DD   1024
#define HH   16
#define DHH  64
#define LLAY 4
#define MM   (BB*TT)          // 4096 rows
#define MD   ((size_t)MM*DD)  // 4,194,304 elements
#define INV_RD (1.0f/32.0f)   // 1/sqrt(D)
#define LNEPS 1e-5f

typedef unsigned short ushort_t;
typedef __attribute__((ext_vector_type(8))) short short8;
typedef __attribute__((ext_vector_type(4))) float floatx4;

__device__ inline ushort_t f2bf(float f) {
  unsigned u = __builtin_bit_cast(unsigned, f);
  unsigned r = (u + 0x7FFFu + ((u >> 16) & 1u)) >> 16;  // RNE
  return (ushort_t)r;
}

// x + pos (pos broadcast over batch); writes fp32 + bf16 copies.
__global__ __launch_bounds__(256) void add_pos_k(const float* __restrict__ x,
                                                 const float* __restrict__ pos,
                                                 float* __restrict__ out,
                                                 ushort_t* __restrict__ out_bf) {
  size_t i = (size_t)blockIdx.x * 256 + threadIdx.x;  // float4 index
  int dq  = (int)(i & 255);
  int row = (int)(i >> 8);
  int t   = row & (TT - 1);
  float4 a = ((const float4*)x)[i];
  float4 p = ((const float4*)pos)[(size_t)t * 256 + dq];
  a.x += p.x; a.y += p.y; a.z += p.z; a.w += p.w;
  ((float4*)out)[i] = a;
  ushort4 b; b.x = f2bf(a.x); b.y = f2bf(a.y); b.z = f2bf(a.z); b.w = f2bf(a.w);
  ((ushort4*)out_bf)[i] = b;
}

// fp32 -> bf16 cast, 4 elems/thread.
__global__ __launch_bounds__(256) void cast_bf_k(const float* __restrict__ in,
                                                 ushort_t* __restrict__ out) {
  size_t i = (size_t)blockIdx.x * 256 + threadIdx.x;
  float4 v = ((const float4*)in)[i];
  ushort4 o; o.x = f2bf(v.x); o.y = f2bf(v.y); o.z = f2bf(v.z); o.w = f2bf(v.w);
  ((ushort4*)out)[i] = o;
}

// LayerNorm: one block per row of D=1024; writes fp32 + bf16 copies.
__global__ __launch_bounds__(256) void ln_k(const float* __restrict__ in,
                                            float* __restrict__ out,
                                            ushort_t* __restrict__ out_bf,
                                            const float* __restrict__ g,
                                            const float* __restrict__ bt) {
  int row = blockIdx.x;
  int t = threadIdx.x;
  const float4* r4 = (const float4*)(in + (size_t)row * DD);
  float4 v = r4[t];
  float s  = v.x + v.y + v.z + v.w;
  float ss = v.x*v.x + v.y*v.y + v.z*v.z + v.w*v.w;
#pragma unroll
  for (int off = 32; off > 0; off >>= 1) {
    s  += __shfl_down(s, off);
    ss += __shfl_down(ss, off);
  }
  __shared__ float red[8];
  int w = t >> 6;
  if ((t & 63) == 0) { red[w] = s; red[4 + w] = ss; }
  __syncthreads();
  s  = red[0] + red[1] + red[2] + red[3];
  ss = red[4] + red[5] + red[6] + red[7];
  float mean = s * (1.0f / DD);
  float var  = ss * (1.0f / DD) - mean * mean;
  float inv  = rsqrtf(var + LNEPS);
  float4 gv = ((const float4*)g)[t];
  float4 bv = ((const float4*)bt)[t];
  float4 o;
  o.x = (v.x - mean) * inv * gv.x + bv.x;
  o.y = (v.y - mean) * inv * gv.y + bv.y;
  o.z = (v.z - mean) * inv * gv.z + bv.z;
  o.w = (v.w - mean) * inv * gv.w + bv.w;
  ((float4*)(out + (size_t)row * DD))[t] = o;
  ushort4 ob; ob.x = f2bf(o.x); ob.y = f2bf(o.y); ob.z = f2bf(o.z); ob.w = f2bf(o.w);
  ((ushort4*)(out_bf + (size_t)row * DD))[t] = ob;
}

// C[m,n] = sum_k A[m,k]*W[n,k], A/W bf16. bf16out selects output dtype.
__global__ __launch_bounds__(256) void gemm_mfma_bt_k(const ushort_t* __restrict__ A,
                                                      const ushort_t* __restrict__ W,
                                                      void* __restrict__ Cout,
                                                      int bf16out) {
  __shared__ ushort_t As[128 * 32];
  __shared__ ushort_t Bs[128 * 32];
  int t = threadIdx.x;
  int n0 = blockIdx.x * 128, m0 = blockIdx.y * 128;
  int lane = t & 63, w = t >> 6;
  int wm = (w >> 1) * 64, wn = (w & 1) * 64;
  int fr = lane & 15, q = lane >> 4;
  const short8* ap[4]; const short8* bp[4];
#pragma unroll
  for (int i = 0; i < 4; i++) {
    int r  = wm + i * 16 + fr;
    int rn = wn + i * 16 + fr;
    ap[i] = (const short8*)(As + r  * 32 + ((q ^ ((r  >> 1) & 3)) * 8));
    bp[i] = (const short8*)(Bs + rn * 32 + ((q ^ ((rn >> 1) & 3)) * 8));
  }
  auto* As3 = (__attribute__((address_space(3))) ushort_t*)As;
  auto* Bs3 = (__attribute__((address_space(3))) ushort_t*)Bs;
  floatx4 acc[4][4] = {};
  for (int k0 = 0; k0 < DD; k0 += 32) {
    __syncthreads();
#pragma unroll
    for (int j = 0; j < 2; j++) {
      int e = t + j * 256;
      int row = e >> 2, slot = e & 3;
      int c = slot ^ ((row >> 1) & 3);
      const ushort_t* asrc = A + (size_t)(m0 + row) * DD + k0 + c * 8;
      const ushort_t* wsrc = W + (size_t)(n0 + row) * DD + k0 + c * 8;
      __builtin_amdgcn_global_load_lds(
          (const __attribute__((address_space(1))) unsigned*)asrc,
          (__attribute__((address_space(3))) unsigned*)(As3 + e * 8), 16, 0, 0);
      __builtin_amdgcn_global_load_lds(
          (const __attribute__((address_space(1))) unsigned*)wsrc,
          (__attribute__((address_space(3))) unsigned*)(Bs3 + e * 8), 16, 0, 0);
    }
    __syncthreads();
    short8 af[4], bf[4];
#pragma unroll
    for (int i = 0; i < 4; i++) { af[i] = *ap[i]; bf[i] = *bp[i]; }
#pragma unroll
    for (int i = 0; i < 4; i++)
#pragma unroll
      for (int j = 0; j < 4; j++)
        acc[i][j] = __builtin_amdgcn_mfma_f32_16x16x32_bf16(af[i], bf[j], acc[i][j], 0, 0, 0);
  }
  int orow = m0 + wm + q * 4;
  int ocol = n0 + wn + fr;
  if (bf16out) {
    ushort_t* Cb = (ushort_t*)Cout;
#pragma unroll
    for (int i = 0; i < 4; i++)
#pragma unroll
      for (int j = 0; j < 4; j++)
#pragma unroll
        for (int rr = 0; rr < 4; rr++)
          Cb[(size_t)(orow + i * 16 + rr) * DD + ocol + j * 16] = f2bf(acc[i][j][rr]);
  } else {
    float* C = (float*)Cout;
#pragma unroll
    for (int i = 0; i < 4; i++)
#pragma unroll
      for (int j = 0; j < 4; j++)
#pragma unroll
        for (int rr = 0; rr < 4; rr++)
          C[(size_t)(orow + i * 16 + rr) * DD + ocol + j * 16] = acc[i][j][rr];
  }
}

// Flash attention, bf16 MFMA. Block: 64 q rows of one (b,h); wave w owns
// q rows [w*16, w*16+16). K chunks of 64 keys. Q,K natural [row][dh] LDS
// (XOR chunk swizzle); V transposed [dh][key] LDS. Online softmax state in
// registers (rows live in lanes' C-layout regs). P LDS round-trip to
// A-operand layout. cross=1: K/V layout (B,H,T,DH) + triangular chunk skip
// + diagonal-chunk mask. Output: resid + O, fp32.
__global__ __launch_bounds__(256) void attn_mfma_k(const ushort_t* __restrict__ Qb,
                                                   const ushort_t* __restrict__ Kb,
                                                   const ushort_t* __restrict__ Vb,
                                                   const float* __restrict__ resid,
                                                   float* __restrict__ out,
                                                   int cross) {
  __shared__ ushort_t Qs[64 * 64];
  __shared__ ushort_t Ks[64 * 64];
  __shared__ ushort_t Vts[64 * 64];
  __shared__ ushort_t Ps[4 * 16 * 64];
  int t = threadIdx.x, lane = t & 63, w = t >> 6;
  int fr = lane & 15, q8 = lane >> 4;
  int qt = blockIdx.x, bh = blockIdx.y;
  int b = bh >> 4, h = bh & 15;
  size_t qbase = ((size_t)(b * TT + qt * 64)) * DD + h * DHH;
  size_t kvbase; int kvstride;
  if (cross) { kvbase = (size_t)bh * TT * DHH;          kvstride = DHH; }
  else       { kvbase = (size_t)b * TT * DD + h * DHH;  kvstride = DD;  }

  auto* Qs3  = (__attribute__((address_space(3))) ushort_t*)Qs;
  auto* Ks3  = (__attribute__((address_space(3))) ushort_t*)Ks;

  // stage Q tile (64 rows x 8 chunks of 8 bf16), source-side swizzle
#pragma unroll
  for (int j = 0; j < 2; j++) {
    int e = t + j * 256;
    int row = e >> 3, slot = e & 7;
    int c = slot ^ (row & 7);
    const ushort_t* src = Qb + qbase + (size_t)row * DD + c * 8;
    __builtin_amdgcn_global_load_lds(
        (const __attribute__((address_space(1))) unsigned*)src,
        (__attribute__((address_space(3))) unsigned*)(Qs3 + e * 8), 16, 0, 0);
  }
  __syncthreads();

  // Q A-fragments: lane holds Q[w*16 + fr][q8*8 + ks*32 .. +8]
  short8 qf[2];
#pragma unroll
  for (int ks = 0; ks < 2; ks++) {
    int row = w * 16 + fr;
    int slot = (ks * 4 + q8) ^ (row & 7);
    qf[ks] = *(const short8*)(Qs + row * 64 + slot * 8);
  }

  float m_i[4], l_i[4];
  floatx4 o_acc[4] = {};
#pragma unroll
  for (int r = 0; r < 4; r++) { m_i[r] = -1e30f; l_i[r] = 0.f; }

  int nch = cross ? (qt + 1) : 8;
  for (int ch = 0; ch < nch; ch++) {
    __syncthreads();   // prior chunk's K/V reads done
    // stage K chunk
#pragma unroll
    for (int j = 0; j < 2; j++) {
      int e = t + j * 256;
      int row = e >> 3, slot = e & 7;
      int c = slot ^ (row & 7);
      const ushort_t* src = Kb + kvbase + (size_t)(ch * 64 + row) * kvstride + c * 8;
      __builtin_amdgcn_global_load_lds(
          (const __attribute__((address_space(1))) unsigned*)src,
          (__attribute__((address_space(3))) unsigned*)(Ks3 + e * 8), 16, 0, 0);
    }
    // stage V transposed: thread owns keys {2kp,2kp+1} x 8 dh
    {
      int kp = t & 31, dhg = (t >> 5) * 8;
      const ushort_t* v0 = Vb + kvbase + (size_t)(ch * 64 + 2 * kp) * kvstride + dhg;
      short8 a0 = *(const short8*)v0;
      short8 a1 = *(const short8*)(v0 + kvstride);
#pragma unroll
      for (int j = 0; j < 8; j++) {
        int dh = dhg + j;
        int slot = (kp >> 2) ^ (dh & 7);
        unsigned pk = (unsigned)(unsigned short)a0[j] |
                      ((unsigned)(unsigned short)a1[j] << 16);
        *(unsigned*)(Vts + dh * 64 + slot * 8 + (kp & 3) * 2) = pk;
      }
    }
    __syncthreads();

    // S = Q K^T (per wave: 16 q x 64 keys), scale, mask
    floatx4 s[4] = {};
#pragma unroll
    for (int nt = 0; nt < 4; nt++) {
      int key = nt * 16 + fr;
#pragma unroll
      for (int ks = 0; ks < 2; ks++) {
        int slot = (ks * 4 + q8) ^ (key & 7);
        short8 kf = *(const short8*)(Ks + key * 64 + slot * 8);
        s[nt] = __builtin_amdgcn_mfma_f32_16x16x32_bf16(qf[ks], kf, s[nt], 0, 0, 0);
      }
    }
    float sv[4][4];
#pragma unroll
    for (int nt = 0; nt < 4; nt++)
#pragma unroll
      for (int r = 0; r < 4; r++)
        sv[nt][r] = s[nt][r] * INV_RD;
    if (cross && ch == qt) {
#pragma unroll
      for (int nt = 0; nt < 4; nt++) {
        int key_g = ch * 64 + nt * 16 + fr;
#pragma unroll
        for (int r = 0; r < 4; r++) {
          int q_g = qt * 64 + w * 16 + q8 * 4 + r;
          if (key_g > q_g) sv[nt][r] = -1e30f;
        }
      }
    }

    // online softmax update (rows = q8*4+r, reduce across fr lanes)
    float pv[4][4];
#pragma unroll
    for (int r = 0; r < 4; r++) {
      float mch = fmaxf(fmaxf(sv[0][r], sv[1][r]), fmaxf(sv[2][r], sv[3][r]));
#pragma unroll
      for (int off = 1; off < 16; off <<= 1) mch = fmaxf(mch, __shfl_xor(mch, off));
      float mn = fmaxf(m_i[r], mch);
      float alpha = __expf(m_i[r] - mn);
      m_i[r] = mn;
      float rs = 0.f;
#pragma unroll
      for (int nt = 0; nt < 4; nt++) {
        float pe = __expf(sv[nt][r] - mn);
        pv[nt][r] = pe; rs += pe;
      }
#pragma unroll
      for (int off = 1; off < 16; off <<= 1) rs += __shfl_xor(rs, off);
      l_i[r] = l_i[r] * alpha + rs;
#pragma unroll
      for (int nt = 0; nt < 4; nt++) o_acc[nt][r] *= alpha;
    }

    // P -> LDS (wave-private), C-layout -> A-layout round trip
    ushort_t* Pw = Ps + w * 1024;
#pragma unroll
    for (int nt = 0; nt < 4; nt++) {
      int col = nt * 16 + fr;
#pragma unroll
      for (int r = 0; r < 4; r++) {
        int row = q8 * 4 + r;
        int slot = (col >> 3) ^ (row & 7);
        Pw[row * 64 + slot * 8 + (col & 7)] = f2bf(pv[nt][r]);
      }
    }
    short8 pf[2];
#pragma unroll
    for (int ks = 0; ks < 2; ks++) {
      int slot = (ks * 4 + q8) ^ (fr & 7);
      pf[ks] = *(const short8*)(Pw + fr * 64 + slot * 8);
    }
    // O += P V  (B-fragment from transposed V)
#pragma unroll
    for (int nt = 0; nt < 4; nt++) {
      int dh = nt * 16 + fr;
#pragma unroll
      for (int ks = 0; ks < 2; ks++) {
        int slot = (ks * 4 + q8) ^ (dh & 7);
        short8 vf = *(const short8*)(Vts + dh * 64 + slot * 8);
        o_acc[nt] = __builtin_amdgcn_mfma_f32_16x16x32_bf16(pf[ks], vf, o_acc[nt], 0, 0, 0);
      }
    }
  }

  // epilogue: O/l + residual
  float invl[4];
#pragma unroll
  for (int r = 0; r < 4; r++) invl[r] = 1.0f / l_i[r];
#pragma unroll
  for (int nt = 0; nt < 4; nt++) {
#pragma unroll
    for (int r = 0; r < 4; r++) {
      size_t row_g = (size_t)(b * TT + qt * 64 + w * 16 + q8 * 4 + r);
      size_t idx = row_g * DD + h * DHH + nt * 16 + fr;
      out[idx] = resid[idx] + o_acc[nt][r] * invl[r];
    }
  }
}

// cur = relu(gemm_out + bias) + ln_out
__global__ __launch_bounds__(256) void fc_ep_k(const float* __restrict__ gout,
                                               const float* __restrict__ bias,
                                               const float* __restrict__ lnout,
                                               float* __restrict__ out) {
  size_t i = (size_t)blockIdx.x * 256 + threadIdx.x;
  int c4 = (int)(i & 255);
  float4 gv = ((const float4*)gout)[i];
  float4 bv = ((const float4*)bias)[c4];
  float4 lv = ((const float4*)lnout)[i];
  float4 o;
  o.x = fmaxf(gv.x + bv.x, 0.f) + lv.x;
  o.y = fmaxf(gv.y + bv.y, 0.f) + lv.y;
  o.z = fmaxf(gv.z + bv.z, 0.f) + lv.z;
  o.w = fmaxf(gv.w + bv.w, 0.f) + lv.w;
  ((float4*)out)[i] = o;
}

// Ordinal sigmoid head.
__global__ __launch_bounds__(256) void head_k(const float* __restrict__ x,
                                              const float* __restrict__ cut,
                                              float* __restrict__ out) {
  __shared__ float obuf[2560];
  int t = threadIdx.x;
  size_t e = (size_t)blockIdx.x * 256 + t;
  float xv = x[e];
  float bj = cut[0];
  float sprev = 1.0f / (1.0f + __expf(xv - bj));
  obuf[t * 10 + 0] = sprev;
#pragma unroll
  for (int j = 1; j < 9; j++) {
    float cj = cut[j];
    bj += cj * cj;
    float sj = 1.0f / (1.0f + __expf(xv - bj));
    obuf[t * 10 + j] = sj - sprev;
    sprev = sj;
  }
  obuf[t * 10 + 9] = 1.0f - sprev;
  __syncthreads();
  size_t base = (size_t)blockIdx.x * 2560;
#pragma unroll
  for (int r = 0; r < 10; r++) out[base + r * 256 + t] = obuf[r * 256 + t];
}

extern "C" void kernel_launch(void* const* d_in, const int* in_sizes, int n_in,
                              void* d_out, int out_size, void* d_ws, size_t ws_size,
                              hipStream_t stream) {
  (void)in_sizes; (void)n_in; (void)out_size; (void)ws_size;
  const float* x    = (const float*)d_in[0];
  const float* kin  = (const float*)d_in[1];
  const float* vin  = (const float*)d_in[2];
  const float* pos  = (const float*)d_in[3];
  const float* Wq1  = (const float*)d_in[4];
  const float* Wk1  = (const float*)d_in[5];
  const float* Wv1  = (const float*)d_in[6];
  const float* Wq2  = (const float*)d_in[7];
  const float* Wfc  = (const float*)d_in[8];
  const float* bfc  = (const float*)d_in[9];
  const float* g1   = (const float*)d_in[10];
  const float* b1   = (const float*)d_in[11];
  const float* g2   = (const float*)d_in[12];
  const float* b2   = (const float*)d_in[13];
  const float* g3   = (const float*)d_in[14];
  const float* b3   = (const float*)d_in[15];
  const float* cut  = (const float*)d_in[16];
  float* out = (float*)d_out;

  // ws (120 MB): cur 16 | tmp 16 | act_bf 8 | qbf 8 | kvregion 16
  //              (kbf+vbf bf16, aliased by qb_f32 for the fc GEMM) |
  //              kinbf 8 | vinbf 8 | wbf 40
  float* cur = (float*)d_ws;
  float* tmp = cur + MD;
  ushort_t* act_bf = (ushort_t*)(tmp + MD);
  ushort_t* qbf    = act_bf + MD;
  ushort_t* kbf    = qbf + MD;
  ushort_t* vbf    = kbf + MD;
  float*    qb32   = (float*)kbf;       // alias: dead when fc GEMM runs
  ushort_t* kinbf  = vbf + MD;
  ushort_t* vinbf  = kinbf + MD;
  ushort_t* wbf[5];
  wbf[0] = vinbf + MD;
  for (int i = 1; i < 5; i++) wbf[i] = wbf[i - 1] + (size_t)LLAY * DD * DD;
  const float* wsrc[5] = {Wq1, Wk1, Wv1, Wq2, Wfc};

  dim3 b256(256);
  dim3 gg(DD / 128, MM / 128);   // (8, 32)
  dim3 ga(TT / 64, BB * HH);     // (8, 128)

  for (int i = 0; i < 5; i++)
    cast_bf_k<<<(LLAY * DD * DD) / 1024, b256, 0, stream>>>(wsrc[i], wbf[i]);
  cast_bf_k<<<MD / 1024, b256, 0, stream>>>(kin, kinbf);
  cast_bf_k<<<MD / 1024, b256, 0, stream>>>(vin, vinbf);

  add_pos_k<<<MD / 1024, b256, 0, stream>>>(x, pos, cur, act_bf);

  for (int i = 0; i < LLAY; i++) {
    const float* attn_in;
    if (i) {
      ln_k<<<MM, b256, 0, stream>>>(cur, tmp, act_bf, g1 + (size_t)(i - 1) * DD, b1 + (size_t)(i - 1) * DD);
      attn_in = tmp;
    } else {
      attn_in = cur;   // act_bf already holds bf16(cur)
    }
    size_t wo = (size_t)i * DD * DD;
    gemm_mfma_bt_k<<<gg, b256, 0, stream>>>(act_bf, wbf[0] + wo, qbf, 1);
    gemm_mfma_bt_k<<<gg, b256, 0, stream>>>(act_bf, wbf[1] + wo, kbf, 1);
    gemm_mfma_bt_k<<<gg, b256, 0, stream>>>(act_bf, wbf[2] + wo, vbf, 1);
    attn_mfma_k<<<ga, b256, 0, stream>>>(qbf, kbf, vbf, attn_in, cur, 0);

    ln_k<<<MM, b256, 0, stream>>>(cur, tmp, act_bf, g2 + (size_t)i * DD, b2 + (size_t)i * DD);
    gemm_mfma_bt_k<<<gg, b256, 0, stream>>>(act_bf, wbf[3] + wo, qbf, 1);
    attn_mfma_k<<<ga, b256, 0, stream>>>(qbf, kinbf, vinbf, tmp, cur, 1);

    ln_k<<<MM, b256, 0, stream>>>(cur, tmp, act_bf, g3 + (size_t)i * DD, b3 + (size_t)i * DD);
    gemm_mfma_bt_k<<<gg, b256, 0, stream>>>(act_bf, wbf[4] + wo, qb32, 0);
    fc_ep_k<<<MD / 1024, b256, 0, stream>>>(qb32, bfc + (size_t)i * DD, tmp, cur);
  }

  head_k<<<MD / 256, b256, 0, stream>>>(cur, cut, out);
}